// Round 5
// baseline (514.448 us; speedup 1.0000x reference)
//
#include <hip/hip_runtime.h>

#define NEG_SLOPE 0.2f

typedef __attribute__((ext_vector_type(8))) short bf16x8;
typedef __attribute__((ext_vector_type(4))) float f32x4;

// leaky_relu(m) = 0.6*m + 0.4*|m| (exact for slope 0.2)
static __device__ __forceinline__ float lrelu(float m) {
    return fmaf(0.4f, fabsf(m), 0.6f * m);
}

static __device__ __forceinline__ float wsum64(float v) {
#pragma unroll
    for (int off = 32; off >= 1; off >>= 1) v += __shfl_xor(v, off, 64);
    return v;
}
static __device__ __forceinline__ float wmax64(float v) {
#pragma unroll
    for (int off = 32; off >= 1; off >>= 1) v = fmaxf(v, __shfl_xor(v, off, 64));
    return v;
}

// fp32 -> bf16 (RNE)
static __device__ __forceinline__ unsigned short bf16r(float a) {
    unsigned int u = __float_as_uint(a);
    return (unsigned short)((u + 0x7FFFu + ((u >> 16) & 1u)) >> 16);
}
static __device__ __forceinline__ unsigned int bf16pack(float a, float b) {
    unsigned int ua = __float_as_uint(a);
    ua = (ua + 0x7FFFu + ((ua >> 16) & 1u)) >> 16;
    unsigned int ub = __float_as_uint(b);
    ub = (ub + 0x7FFFu + ((ub >> 16) & 1u)) & 0xFFFF0000u;
    return ua | ub;
}
// expand 8 bf16 (uint4) -> 8 floats
static __device__ __forceinline__ void expand8(uint4 u, float* o) {
    o[0] = __uint_as_float(u.x << 16); o[1] = __uint_as_float(u.x & 0xFFFF0000u);
    o[2] = __uint_as_float(u.y << 16); o[3] = __uint_as_float(u.y & 0xFFFF0000u);
    o[4] = __uint_as_float(u.z << 16); o[5] = __uint_as_float(u.z & 0xFFFF0000u);
    o[6] = __uint_as_float(u.w << 16); o[7] = __uint_as_float(u.w & 0xFFFF0000u);
}
// expand 4 bf16 (uint2) -> 4 floats
static __device__ __forceinline__ void expand4(uint2 u, float* o) {
    o[0] = __uint_as_float(u.x << 16); o[1] = __uint_as_float(u.x & 0xFFFF0000u);
    o[2] = __uint_as_float(u.y << 16); o[3] = __uint_as_float(u.y & 0xFFFF0000u);
}
static __device__ __forceinline__ void load16(const float* p, float* o) {
#pragma unroll
    for (int j = 0; j < 4; ++j) {
        float4 v = ((const float4*)p)[j];
        o[j * 4 + 0] = v.x; o[j * 4 + 1] = v.y; o[j * 4 + 2] = v.z; o[j * 4 + 3] = v.w;
    }
}

// ---------- init ----------
__global__ void k_zero_all(int* __restrict__ cntF, int n3, int* __restrict__ cnt3,
                           int* __restrict__ gsum) {
    int i = blockIdx.x * blockDim.x + threadIdx.x;
    if (i < n3) cntF[i] = 0;
    if (i < 4) cnt3[i] = 0;
    if (i < 32) gsum[i] = 0;
}

// fused: (dst,flow) histogram + global flow counts
__global__ void k_edges(const int* __restrict__ ei, const int* __restrict__ ea,
                        int* __restrict__ cntF, int* __restrict__ cnt3, int E) {
    __shared__ int sh3[3];
    if (threadIdx.x < 3) sh3[threadIdx.x] = 0;
    __syncthreads();
    int e = blockIdx.x * blockDim.x + threadIdx.x;
    if (e < E) {
        int dd = ei[E + e];
        int f = ea[2 * e];
        f = f < 0 ? 0 : (f > 2 ? 2 : f);
        atomicAdd(&cntF[dd * 3 + f], 1);
        atomicAdd(&sh3[f], 1);
    }
    __syncthreads();
    if (threadIdx.x < 3) atomicAdd(&cnt3[threadIdx.x], sh3[threadIdx.x]);
}

// block 0: constant edge-attr projections (posc is constant: clip(where(pos>MP,pos,MP),0,MP)==MP).
// blocks 1..: bf16 n-major weight copies Bt1[512][128], Bt2[64][256].
__global__ void k_prep_all(const float* __restrict__ pos_table, const float* __restrict__ pos_W,
                           const float* __restrict__ pos_b, const float* __restrict__ flow_emb,
                           const float* __restrict__ We1, const float* __restrict__ We2,
                           const int* __restrict__ cnt3,
                           float* __restrict__ eaW1, float* __restrict__ loopW1,
                           float* __restrict__ eaW2, float* __restrict__ loopW2,
                           const float* __restrict__ Wl1, const float* __restrict__ Wr1,
                           const float* __restrict__ Wl2, const float* __restrict__ Wr2,
                           unsigned short* __restrict__ Bt1, unsigned short* __restrict__ Bt2,
                           int E) {
    if (blockIdx.x != 0) {
        int i = (blockIdx.x - 1) * 256 + threadIdx.x;
        if (i < 512 * 128) {
            int nn = i >> 7, k = i & 127;
            float v = (nn < 256) ? Wl1[(size_t)k * 256 + nn] : Wr1[(size_t)k * 256 + nn - 256];
            Bt1[i] = bf16r(v);
        } else {
            int j = i - 512 * 128;
            if (j < 64 * 256) {
                int nn = j >> 8, k = j & 255;
                float v = (nn < 32) ? Wl2[(size_t)k * 32 + nn] : Wr2[(size_t)k * 32 + nn - 32];
                Bt2[j] = bf16r(v);
            }
        }
        return;
    }
    __shared__ float posc[128];
    __shared__ float lv[128];
    int t = threadIdx.x;
    if (t < 128) {
        const float* row = pos_table + 5120 * 128;
        float a = pos_b[t];
        for (int k = 0; k < 128; ++k) a += row[k] * pos_W[k * 128 + t];
        posc[t] = a;
        float invE = 1.0f / (float)E;
        lv[t] = ((float)cnt3[0] * flow_emb[t] + (float)cnt3[1] * flow_emb[128 + t] +
                 (float)cnt3[2] * flow_emb[256 + t]) * invE + a;
    }
    __syncthreads();
    {   // layer 1 projections, j = 0..255
        int j = t;
        float a0 = 0.f, a1 = 0.f, a2 = 0.f, al = 0.f;
        for (int k = 0; k < 128; ++k) {
            float w = We1[k * 256 + j];
            float pc = posc[k];
            a0 += (flow_emb[k] + pc) * w;
            a1 += (flow_emb[128 + k] + pc) * w;
            a2 += (flow_emb[256 + k] + pc) * w;
            al += lv[k] * w;
        }
        eaW1[j] = a0; eaW1[256 + j] = a1; eaW1[512 + j] = a2; loopW1[j] = al;
    }
    if (t < 32) {  // layer 2 projections
        int j = t;
        float a0 = 0.f, a1 = 0.f, a2 = 0.f, al = 0.f;
        for (int k = 0; k < 128; ++k) {
            float w = We2[k * 32 + j];
            float pc = posc[k];
            a0 += (flow_emb[k] + pc) * w;
            a1 += (flow_emb[128 + k] + pc) * w;
            a2 += (flow_emb[256 + k] + pc) * w;
            al += lv[k] * w;
        }
        eaW2[j] = a0; eaW2[32 + j] = a1; eaW2[64 + j] = a2; loopW2[j] = al;
    }
}

// ---------- CSR over 3N (dst,flow) keys ----------
__global__ __launch_bounds__(256) void k_scan_block(const int* __restrict__ cnt,
                                                    int* __restrict__ rowptr,
                                                    int* __restrict__ bsum, int n) {
    __shared__ int sh[256];
    int b = blockIdx.x, t = threadIdx.x;
    int base = b * 1024 + t * 4;
    int v0 = base + 0 < n ? cnt[base + 0] : 0;
    int v1 = base + 1 < n ? cnt[base + 1] : 0;
    int v2 = base + 2 < n ? cnt[base + 2] : 0;
    int v3 = base + 3 < n ? cnt[base + 3] : 0;
    int tot = v0 + v1 + v2 + v3;
    sh[t] = tot;
    __syncthreads();
    for (int off = 1; off < 256; off <<= 1) {
        int x = (t >= off) ? sh[t - off] : 0;
        __syncthreads();
        sh[t] += x;
        __syncthreads();
    }
    int excl = (t > 0) ? sh[t - 1] : 0;
    if (base + 0 < n) rowptr[base + 0] = excl;
    if (base + 1 < n) rowptr[base + 1] = excl + v0;
    if (base + 2 < n) rowptr[base + 2] = excl + v0 + v1;
    if (base + 3 < n) rowptr[base + 3] = excl + v0 + v1 + v2;
    if (t == 255) bsum[b] = sh[255];
}

__global__ void k_scan_top(int* __restrict__ bsum, int* __restrict__ rowptr, int nb, int n) {
    if (threadIdx.x == 0 && blockIdx.x == 0) {
        int run = 0;
        for (int b = 0; b < nb; ++b) { int x = bsum[b]; bsum[b] = run; run += x; }
        rowptr[n] = run;
    }
}

__global__ void k_scan_add(int* __restrict__ rowptr, const int* __restrict__ bsum,
                           int* __restrict__ wptr, int n) {
    int i = blockIdx.x * blockDim.x + threadIdx.x;
    if (i < n) {
        int v = rowptr[i] + bsum[i >> 10];
        rowptr[i] = v;
        wptr[i] = v;
    }
}

// scatter src ids into (dst,flow)-sorted order
__global__ void k_scatter(const int* __restrict__ ei, const int* __restrict__ ea,
                          int* __restrict__ wptr, int* __restrict__ packed, int E) {
    int e = blockIdx.x * blockDim.x + threadIdx.x;
    if (e >= E) return;
    int s = ei[e], dd = ei[E + e];
    int f = ea[2 * e];
    f = f < 0 ? 0 : (f > 2 ? 2 : f);
    int p = atomicAdd(&wptr[dd * 3 + f], 1);
    packed[p] = s;
}

// ---------- GEMM 1 (MFMA): xc[N][512] = [h @ Wl+bl | h @ Wr+br], bf16 ----------
__global__ __launch_bounds__(256) void k_gemm1(const int* __restrict__ x,
        const float* __restrict__ text_emb, const float* __restrict__ type_emb,
        const unsigned short* __restrict__ Bt,  // [512][128] bf16, n-major
        const float* __restrict__ bl, const float* __restrict__ br,
        unsigned short* __restrict__ xc, int n) {
    __shared__ unsigned short Ash[64][136];
    __shared__ unsigned short Bsh[128][136];
    int t = threadIdx.x;
    int node0 = blockIdx.x * 64;
    for (int i = t; i < 64 * 128; i += 256) {
        int r = i >> 7, cc = i & 127;
        int nd = node0 + r;
        float v = 0.f;
        if (nd < n)
            v = (cc < 64) ? text_emb[(size_t)x[nd * 2] * 64 + cc]
                          : type_emb[(size_t)x[nd * 2 + 1] * 64 + (cc - 64)];
        Ash[r][cc] = bf16r(v);
    }
    int wave = t >> 6, lane = t & 63;
    int m = lane & 15, q = lane >> 4;
    for (int nb = 0; nb < 4; ++nb) {
        __syncthreads();
        for (int i = t; i < 128 * 16; i += 256) {
            int r = i >> 4, cs = i & 15;
            uint4 v = ((const uint4*)(Bt + (size_t)(nb * 128 + r) * 128))[cs];
            *(uint4*)&Bsh[r][cs * 8] = v;
        }
        __syncthreads();
        f32x4 acc[8];
#pragma unroll
        for (int nt = 0; nt < 8; ++nt) acc[nt] = (f32x4){0.f, 0.f, 0.f, 0.f};
#pragma unroll
        for (int k = 0; k < 128; k += 32) {
            bf16x8 a = *(const bf16x8*)&Ash[wave * 16 + m][k + q * 8];
#pragma unroll
            for (int nt = 0; nt < 8; ++nt) {
                bf16x8 b = *(const bf16x8*)&Bsh[nt * 16 + m][k + q * 8];
                acc[nt] = __builtin_amdgcn_mfma_f32_16x16x32_bf16(a, b, acc[nt], 0, 0, 0);
            }
        }
#pragma unroll
        for (int r = 0; r < 4; ++r) {
            int node = node0 + wave * 16 + q * 4 + r;
            if (node < n) {
                unsigned short* rowp = xc + (size_t)node * 512 + nb * 128 + m;
#pragma unroll
                for (int nt = 0; nt < 8; ++nt) {
                    int ng = nb * 128 + nt * 16 + m;
                    float bv = (ng < 256) ? bl[ng] : br[ng - 256];
                    rowp[nt * 16] = bf16r(acc[nt][r] + bv);
                }
            }
        }
    }
}

// ---------- GEMM 2 (MFMA): xc2[N][64] = [h2 @ Wl+bl | h2 @ Wr+br], bf16 ----------
__global__ __launch_bounds__(256) void k_gemm2(const unsigned short* __restrict__ h2b,
        const unsigned short* __restrict__ Bt,  // [64][256] bf16, n-major
        const float* __restrict__ bl, const float* __restrict__ br,
        unsigned short* __restrict__ xc, int n) {
    __shared__ unsigned short Ash[32][264];
    __shared__ unsigned short Bsh[64][264];
    int t = threadIdx.x;
    int node0 = blockIdx.x * 32;
    for (int i = t; i < 32 * 32; i += 256) {
        int r = i >> 5, cs = i & 31;
        int nd = node0 + r;
        uint4 v = make_uint4(0u, 0u, 0u, 0u);
        if (nd < n) v = ((const uint4*)(h2b + (size_t)nd * 256))[cs];
        *(uint4*)&Ash[r][cs * 8] = v;
    }
    for (int i = t; i < 64 * 32; i += 256) {
        int r = i >> 5, cs = i & 31;
        uint4 v = ((const uint4*)(Bt + (size_t)r * 256))[cs];
        *(uint4*)&Bsh[r][cs * 8] = v;
    }
    __syncthreads();
    int wave = t >> 6, lane = t & 63;
    int m = lane & 15, q = lane >> 4;
    int mrow = (wave >> 1) * 16;
    int nh   = (wave & 1) * 32;
    f32x4 acc[2];
    acc[0] = (f32x4){0.f, 0.f, 0.f, 0.f};
    acc[1] = (f32x4){0.f, 0.f, 0.f, 0.f};
#pragma unroll
    for (int k = 0; k < 256; k += 32) {
        bf16x8 a = *(const bf16x8*)&Ash[mrow + m][k + q * 8];
#pragma unroll
        for (int nt = 0; nt < 2; ++nt) {
            bf16x8 b = *(const bf16x8*)&Bsh[nh + nt * 16 + m][k + q * 8];
            acc[nt] = __builtin_amdgcn_mfma_f32_16x16x32_bf16(a, b, acc[nt], 0, 0, 0);
        }
    }
#pragma unroll
    for (int r = 0; r < 4; ++r) {
        int node = node0 + mrow + q * 4 + r;
        if (node < n) {
#pragma unroll
            for (int nt = 0; nt < 2; ++nt) {
                int ng = nh + nt * 16 + m;
                float bv = (ng < 32) ? bl[ng] : br[ng - 32];
                xc[(size_t)node * 64 + ng] = bf16r(acc[nt][r] + bv);
            }
        }
    }
}

// ---------- GAT layer 1: wave per dst, 4 groups x 16 lanes, 16 dims/lane ----------
// Flow-sorted CSR: per dst three runs -> flow vector is loop-constant (no selects).
__global__ __launch_bounds__(256) void k_gat256(const unsigned short* __restrict__ xc1,
        const int* __restrict__ rowptrF, const int* __restrict__ packed,
        const float* __restrict__ eaW, const float* __restrict__ loopW,
        const float* __restrict__ att, const float* __restrict__ bias,
        unsigned short* __restrict__ h2b, int n) {
    int wid = (blockIdx.x * blockDim.x + threadIdx.x) >> 6;
    if (wid >= n) return;
    int lane = threadIdx.x & 63;
    int g = lane >> 4, li = lane & 15;
    int d = wid;
    int cb = li * 16;
    const uint4* rxl = (const uint4*)(xc1 + (size_t)d * 512);
    const uint4* rxr = (const uint4*)(xc1 + (size_t)d * 512 + 256);
    uint4 ul0 = rxl[li * 2], ul1 = rxl[li * 2 + 1];
    uint4 ur0 = rxr[li * 2], ur1 = rxr[li * 2 + 1];
    float xld[16], xrd[16];
    expand8(ul0, xld); expand8(ul1, xld + 8);
    expand8(ur0, xrd); expand8(ur1, xrd + 8);
    float av[16], r0[16], r1[16], r2[16], lw[16];
    load16(att + cb, av);
    load16(eaW + cb, r0);
    load16(eaW + 256 + cb, r1);
    load16(eaW + 512 + cb, r2);
    load16(loopW + cb, lw);
#pragma unroll
    for (int i = 0; i < 16; ++i) {
        r0[i] += xrd[i]; r1[i] += xrd[i]; r2[i] += xrd[i]; lw[i] += xrd[i];
    }
    // self-loop score (16-lane group reduce; identical in all 4 groups)
    float qs = 0.f;
#pragma unroll
    for (int i = 0; i < 16; ++i) qs += lrelu(xld[i] + lw[i]) * av[i];
    qs += __shfl_xor(qs, 1, 64); qs += __shfl_xor(qs, 2, 64);
    qs += __shfl_xor(qs, 4, 64); qs += __shfl_xor(qs, 8, 64);
    float wself = __expf(qs);
    float den = (g == 0) ? wself : 0.f;
    float acc[16];
#pragma unroll
    for (int i = 0; i < 16; ++i) acc[i] = (g == 0) ? wself * xld[i] : 0.f;

    int b0 = rowptrF[d * 3], b1 = rowptrF[d * 3 + 1];
    int b2 = rowptrF[d * 3 + 2], b3 = rowptrF[d * 3 + 3];

    auto edge = [&](int p, const float* pre) {
        int s = packed[p];
        const uint4* rs = (const uint4*)(xc1 + (size_t)s * 512);
        uint4 u0 = rs[li * 2], u1 = rs[li * 2 + 1];
        float xs[16];
        expand8(u0, xs); expand8(u1, xs + 8);
        float qp = 0.f;
#pragma unroll
        for (int i = 0; i < 16; ++i) qp += lrelu(xs[i] + pre[i]) * av[i];
        qp += __shfl_xor(qp, 1, 64); qp += __shfl_xor(qp, 2, 64);
        qp += __shfl_xor(qp, 4, 64); qp += __shfl_xor(qp, 8, 64);
        float w = __expf(qp);
        den += w;
#pragma unroll
        for (int i = 0; i < 16; ++i) acc[i] = fmaf(w, xs[i], acc[i]);
    };
    auto run = [&](int pA, int pB, const float* pre) {
        int p = pA + g;
        for (; p + 4 < pB; p += 8) {  // two independent edges in flight
            int s0 = packed[p], s1 = packed[p + 4];
            const uint4* ra = (const uint4*)(xc1 + (size_t)s0 * 512);
            const uint4* rb = (const uint4*)(xc1 + (size_t)s1 * 512);
            uint4 a0 = ra[li * 2], a1 = ra[li * 2 + 1];
            uint4 c0 = rb[li * 2], c1 = rb[li * 2 + 1];
            float xa[16], xb[16];
            expand8(a0, xa); expand8(a1, xa + 8);
            expand8(c0, xb); expand8(c1, xb + 8);
            float qa = 0.f, qb = 0.f;
#pragma unroll
            for (int i = 0; i < 16; ++i) {
                qa += lrelu(xa[i] + pre[i]) * av[i];
                qb += lrelu(xb[i] + pre[i]) * av[i];
            }
#pragma unroll
            for (int off = 1; off <= 8; off <<= 1) {
                qa += __shfl_xor(qa, off, 64);
                qb += __shfl_xor(qb, off, 64);
            }
            float wa = __expf(qa), wb = __expf(qb);
            den += wa + wb;
#pragma unroll
            for (int i = 0; i < 16; ++i)
                acc[i] = fmaf(wb, xb[i], fmaf(wa, xa[i], acc[i]));
        }
        if (p < pB) edge(p, pre);
    };
    run(b0, b1, r0);
    run(b1, b2, r1);
    run(b2, b3, r2);

    // combine the 4 groups
#pragma unroll
    for (int i = 0; i < 16; ++i) {
        acc[i] += __shfl_xor(acc[i], 16, 64);
        acc[i] += __shfl_xor(acc[i], 32, 64);
    }
    den += __shfl_xor(den, 16, 64);
    den += __shfl_xor(den, 32, 64);
    if (g == 0) {
        float bv[16];
        load16(bias + cb, bv);
        float inv = 1.f / den;
        uint4 o0, o1;
        o0.x = bf16pack(fmaf(acc[0], inv, bv[0]),  fmaf(acc[1], inv, bv[1]));
        o0.y = bf16pack(fmaf(acc[2], inv, bv[2]),  fmaf(acc[3], inv, bv[3]));
        o0.z = bf16pack(fmaf(acc[4], inv, bv[4]),  fmaf(acc[5], inv, bv[5]));
        o0.w = bf16pack(fmaf(acc[6], inv, bv[6]),  fmaf(acc[7], inv, bv[7]));
        o1.x = bf16pack(fmaf(acc[8], inv, bv[8]),  fmaf(acc[9], inv, bv[9]));
        o1.y = bf16pack(fmaf(acc[10], inv, bv[10]), fmaf(acc[11], inv, bv[11]));
        o1.z = bf16pack(fmaf(acc[12], inv, bv[12]), fmaf(acc[13], inv, bv[13]));
        o1.w = bf16pack(fmaf(acc[14], inv, bv[14]), fmaf(acc[15], inv, bv[15]));
        uint4* orow = (uint4*)(h2b + (size_t)d * 256);
        orow[li * 2] = o0;
        orow[li * 2 + 1] = o1;
    }
}

// ---------- GAT layer 2: wave per dst, 8 groups x 8 lanes, 4 dims/lane ----------
__global__ __launch_bounds__(256) void k_gat32(const unsigned short* __restrict__ xc2,
        const int* __restrict__ rowptrF, const int* __restrict__ packed,
        const float* __restrict__ eaW, const float* __restrict__ loopW,
        const float* __restrict__ att, const float* __restrict__ bias,
        float* __restrict__ out, int n) {
    int wid = (blockIdx.x * blockDim.x + threadIdx.x) >> 6;
    if (wid >= n) return;
    int lane = threadIdx.x & 63;
    int g = lane >> 3, li = lane & 7;
    int d = wid;
    int cb = li * 4;
    uint2 uxl = ((const uint2*)(xc2 + (size_t)d * 64))[li];
    uint2 uxr = ((const uint2*)(xc2 + (size_t)d * 64 + 32))[li];
    float xld[4], xrd[4];
    expand4(uxl, xld); expand4(uxr, xrd);
    float4 avv = ((const float4*)att)[li];
    float av[4] = {avv.x, avv.y, avv.z, avv.w};
    float4 e0 = ((const float4*)eaW)[li];
    float4 e1 = ((const float4*)(eaW + 32))[li];
    float4 e2 = ((const float4*)(eaW + 64))[li];
    float4 lwv = ((const float4*)loopW)[li];
    float r0[4] = {e0.x + xrd[0], e0.y + xrd[1], e0.z + xrd[2], e0.w + xrd[3]};
    float r1[4] = {e1.x + xrd[0], e1.y + xrd[1], e1.z + xrd[2], e1.w + xrd[3]};
    float r2[4] = {e2.x + xrd[0], e2.y + xrd[1], e2.z + xrd[2], e2.w + xrd[3]};
    float lw[4] = {lwv.x + xrd[0], lwv.y + xrd[1], lwv.z + xrd[2], lwv.w + xrd[3]};
    float qs = 0.f;
#pragma unroll
    for (int i = 0; i < 4; ++i) qs += lrelu(xld[i] + lw[i]) * av[i];
    qs += __shfl_xor(qs, 1, 64); qs += __shfl_xor(qs, 2, 64); qs += __shfl_xor(qs, 4, 64);
    float wself = __expf(qs);
    float den = (g == 0) ? wself : 0.f;
    float acc[4];
#pragma unroll
    for (int i = 0; i < 4; ++i) acc[i] = (g == 0) ? wself * xld[i] : 0.f;

    int b0 = rowptrF[d * 3], b1 = rowptrF[d * 3 + 1];
    int b2 = rowptrF[d * 3 + 2], b3 = rowptrF[d * 3 + 3];

    auto edge = [&](int p, const float* pre) {
        int s = packed[p];
        uint2 u = ((const uint2*)(xc2 + (size_t)s * 64))[li];
        float xs[4];
        expand4(u, xs);
        float qp = 0.f;
#pragma unroll
        for (int i = 0; i < 4; ++i) qp += lrelu(xs[i] + pre[i]) * av[i];
        qp += __shfl_xor(qp, 1, 64); qp += __shfl_xor(qp, 2, 64); qp += __shfl_xor(qp, 4, 64);
        float w = __expf(qp);
        den += w;
#pragma unroll
        for (int i = 0; i < 4; ++i) acc[i] = fmaf(w, xs[i], acc[i]);
    };
    auto run = [&](int pA, int pB, const float* pre) {
        int p = pA + g;
        for (; p + 8 < pB; p += 16) {
            int s0 = packed[p], s1 = packed[p + 8];
            uint2 ua = ((const uint2*)(xc2 + (size_t)s0 * 64))[li];
            uint2 ub = ((const uint2*)(xc2 + (size_t)s1 * 64))[li];
            float xa[4], xb[4];
            expand4(ua, xa); expand4(ub, xb);
            float qa = 0.f, qb = 0.f;
#pragma unroll
            for (int i = 0; i < 4; ++i) {
                qa += lrelu(xa[i] + pre[i]) * av[i];
                qb += lrelu(xb[i] + pre[i]) * av[i];
            }
#pragma unroll
            for (int off = 1; off <= 4; off <<= 1) {
                qa += __shfl_xor(qa, off, 64);
                qb += __shfl_xor(qb, off, 64);
            }
            float wa = __expf(qa), wb = __expf(qb);
            den += wa + wb;
#pragma unroll
            for (int i = 0; i < 4; ++i)
                acc[i] = fmaf(wb, xb[i], fmaf(wa, xa[i], acc[i]));
        }
        if (p < pB) edge(p, pre);
    };
    run(b0, b1, r0);
    run(b1, b2, r1);
    run(b2, b3, r2);

#pragma unroll
    for (int i = 0; i < 4; ++i) {
        acc[i] += __shfl_xor(acc[i], 8, 64);
        acc[i] += __shfl_xor(acc[i], 16, 64);
        acc[i] += __shfl_xor(acc[i], 32, 64);
    }
    den += __shfl_xor(den, 8, 64);
    den += __shfl_xor(den, 16, 64);
    den += __shfl_xor(den, 32, 64);
    if (g == 0) {
        float4 bvv = ((const float4*)bias)[li];
        float inv = 1.f / den;
        float4 o;
        o.x = fmaf(acc[0], inv, bvv.x);
        o.y = fmaf(acc[1], inv, bvv.y);
        o.z = fmaf(acc[2], inv, bvv.z);
        o.w = fmaf(acc[3], inv, bvv.w);
        ((float4*)(out + (size_t)d * 32))[li] = o;
    }
}

// ---------- mean over nodes + policy head ----------
__global__ __launch_bounds__(256) void k_mean(const float* __restrict__ out2,
                                              float* __restrict__ gsum, int n) {
    __shared__ float sh[256];
    int t = threadIdx.x;
    int c = t & 31, g = t >> 5;
    float acc = 0.f;
    for (int nd = blockIdx.x * 8 + g; nd < n; nd += gridDim.x * 8)
        acc += out2[(size_t)nd * 32 + c];
    sh[t] = acc;
    __syncthreads();
    if (t < 32) {
        float s2 = 0.f;
#pragma unroll
        for (int gg = 0; gg < 8; ++gg) s2 += sh[gg * 32 + c];
        atomicAdd(&gsum[c], s2);
    }
}

__global__ void k_final(const float* __restrict__ gsum, const float* __restrict__ policy_W,
                        const float* __restrict__ policy_b, float* __restrict__ out, int n) {
    int t = threadIdx.x;  // 0..63 — one wave
    float invN = 1.0f / (float)n;
    float acc = policy_b[t];
    for (int cc = 0; cc < 32; ++cc) acc += gsum[cc] * invN * policy_W[cc * 64 + t];
    float mx = wmax64(acc);
    float ex = __expf(acc - mx);
    float s = wsum64(ex);
    out[t] = ex / s;
}

extern "C" void kernel_launch(void* const* d_in, const int* in_sizes, int n_in,
                              void* d_out, int out_size, void* d_ws, size_t ws_size,
                              hipStream_t stream) {
    const int* x          = (const int*)d_in[0];
    const int* edge_index = (const int*)d_in[1];
    const int* edge_attr  = (const int*)d_in[2];
    const float* text_emb = (const float*)d_in[3];
    const float* type_emb = (const float*)d_in[4];
    const float* flow_emb = (const float*)d_in[5];
    const float* pos_table= (const float*)d_in[6];
    const float* pos_W    = (const float*)d_in[7];
    const float* pos_b    = (const float*)d_in[8];
    const float* c1_Wl    = (const float*)d_in[9];
    const float* c1_bl    = (const float*)d_in[10];
    const float* c1_Wr    = (const float*)d_in[11];
    const float* c1_br    = (const float*)d_in[12];
    const float* c1_We    = (const float*)d_in[13];
    const float* c1_att   = (const float*)d_in[14];
    const float* c1_bias  = (const float*)d_in[15];
    const float* c2_Wl    = (const float*)d_in[16];
    const float* c2_bl    = (const float*)d_in[17];
    const float* c2_Wr    = (const float*)d_in[18];
    const float* c2_br    = (const float*)d_in[19];
    const float* c2_We    = (const float*)d_in[20];
    const float* c2_att   = (const float*)d_in[21];
    const float* c2_bias  = (const float*)d_in[22];
    const float* policy_W = (const float*)d_in[23];
    const float* policy_b = (const float*)d_in[24];
    float* out = (float*)d_out;

    const int N = in_sizes[0] / 2;   // 50000
    const int E = in_sizes[1] / 2;   // 800000
    const int n3 = 3 * N;

    // ---- workspace layout (256B-aligned chunks) ----
    char* base = (char*)d_ws;
    size_t off = 0;
    auto alloc = [&](size_t bytes) -> void* {
        void* p = base + off;
        off = (off + bytes + 255) & ~(size_t)255;
        return p;
    };
    unsigned short* xc1  = (unsigned short*)alloc((size_t)N * 512 * 2);  // xl1|xr1 bf16
    unsigned short* h2b  = (unsigned short*)alloc((size_t)N * 256 * 2);  // h2 bf16
    unsigned short* xc2  = (unsigned short*)alloc((size_t)N * 64 * 2);   // xl2|xr2 bf16
    float*          out2 = (float*)alloc((size_t)N * 32 * 4);
    unsigned short* Bt1  = (unsigned short*)alloc((size_t)512 * 128 * 2);
    unsigned short* Bt2  = (unsigned short*)alloc((size_t)64 * 256 * 2);
    int*            cntF   = (int*)alloc((size_t)n3 * 4);       // (dst,flow) histogram / cursors
    int*            rowptrF= (int*)alloc((size_t)(n3 + 1) * 4);
    int*            packed = (int*)alloc((size_t)E * 4);
    int*            bsum   = (int*)alloc(256 * 4);
    int*            cnt3   = (int*)alloc(4 * 4);
    float*          eaW1   = (float*)alloc(768 * 4);
    float*          loopW1 = (float*)alloc(256 * 4);
    float*          eaW2   = (float*)alloc(96 * 4);
    float*          loopW2 = (float*)alloc(32 * 4);
    float*          gsum   = (float*)alloc(32 * 4);

    // ---- init (ws is poisoned 0xAA every call) ----
    k_zero_all<<<(n3 + 255) / 256, 256, 0, stream>>>(cntF, n3, cnt3, (int*)gsum);

    // ---- (dst,flow) histogram + flow counts; tables + weight conversion ----
    k_edges<<<(E + 255) / 256, 256, 0, stream>>>(edge_index, edge_attr, cntF, cnt3, E);
    k_prep_all<<<1 + (512 * 128 + 64 * 256) / 256, 256, 0, stream>>>(
        pos_table, pos_W, pos_b, flow_emb, c1_We, c2_We, cnt3,
        eaW1, loopW1, eaW2, loopW2, c1_Wl, c1_Wr, c2_Wl, c2_Wr, Bt1, Bt2, E);

    // ---- CSR build over 3N keys ((dst,flow)-sorted edge list) ----
    int nb = (n3 + 1023) / 1024;
    k_scan_block<<<nb, 256, 0, stream>>>(cntF, rowptrF, bsum, n3);
    k_scan_top<<<1, 64, 0, stream>>>(bsum, rowptrF, nb, n3);
    k_scan_add<<<(n3 + 255) / 256, 256, 0, stream>>>(rowptrF, bsum, cntF, n3);
    k_scatter<<<(E + 255) / 256, 256, 0, stream>>>(edge_index, edge_attr, cntF, packed, E);

    // ---- layer 1 ----
    k_gemm1<<<(N + 63) / 64, 256, 0, stream>>>(x, text_emb, type_emb, Bt1,
                                               c1_bl, c1_br, xc1, N);
    k_gat256<<<(N + 3) / 4, 256, 0, stream>>>(xc1, rowptrF, packed, eaW1, loopW1,
                                              c1_att, c1_bias, h2b, N);

    // ---- layer 2 ----
    k_gemm2<<<(N + 31) / 32, 256, 0, stream>>>(h2b, Bt2, c2_bl, c2_br, xc2, N);
    k_gat32<<<(N + 3) / 4, 256, 0, stream>>>(xc2, rowptrF, packed, eaW2, loopW2,
                                             c2_att, c2_bias, out2, N);

    // ---- readout ----
    k_mean<<<256, 256, 0, stream>>>(out2, gsum, N);
    k_final<<<1, 64, 0, stream>>>(gsum, policy_W, policy_b, out, N);
}

// Round 6
// 470.212 us; speedup vs baseline: 1.0941x; 1.0941x over previous
//
#include <hip/hip_runtime.h>

#define NEG_SLOPE 0.2f

typedef __attribute__((ext_vector_type(8))) short bf16x8;
typedef __attribute__((ext_vector_type(4))) float f32x4;

static __device__ __forceinline__ float wsum64(float v) {
#pragma unroll
    for (int off = 32; off >= 1; off >>= 1) v += __shfl_xor(v, off, 64);
    return v;
}
static __device__ __forceinline__ float wmax64(float v) {
#pragma unroll
    for (int off = 32; off >= 1; off >>= 1) v = fmaxf(v, __shfl_xor(v, off, 64));
    return v;
}

// fp32 -> bf16 (RNE)
static __device__ __forceinline__ unsigned short bf16r(float a) {
    unsigned int u = __float_as_uint(a);
    return (unsigned short)((u + 0x7FFFu + ((u >> 16) & 1u)) >> 16);
}
static __device__ __forceinline__ unsigned int bf16pack(float a, float b) {
    unsigned int ua = __float_as_uint(a);
    ua = (ua + 0x7FFFu + ((ua >> 16) & 1u)) >> 16;
    unsigned int ub = __float_as_uint(b);
    ub = (ub + 0x7FFFu + ((ub >> 16) & 1u)) & 0xFFFF0000u;
    return ua | ub;
}
// expand 4 bf16 (uint2) -> float4
static __device__ __forceinline__ float4 bf16x4_to_f4(uint2 u) {
    float4 v;
    v.x = __uint_as_float(u.x << 16);
    v.y = __uint_as_float(u.x & 0xFFFF0000u);
    v.z = __uint_as_float(u.y << 16);
    v.w = __uint_as_float(u.y & 0xFFFF0000u);
    return v;
}

// score partial: sum_i 0.6*av_i*m_i + 0.4*av_i*|m_i|  (leaky-relu folded; abs is free)
static __device__ __forceinline__ float sdot4(const float4 xs, const float4 pre,
                                              const float4 av6, const float4 av4) {
    float m0 = xs.x + pre.x, m1 = xs.y + pre.y;
    float m2 = xs.z + pre.z, m3 = xs.w + pre.w;
    float q = av6.x * m0 + av4.x * fabsf(m0);
    q = fmaf(av6.y, m1, q); q = fmaf(av4.y, fabsf(m1), q);
    q = fmaf(av6.z, m2, q); q = fmaf(av4.z, fabsf(m2), q);
    q = fmaf(av6.w, m3, q); q = fmaf(av4.w, fabsf(m3), q);
    return q;
}

// fused: (dst,flow) histogram + global flow counts
__global__ void k_edges(const int* __restrict__ ei, const int* __restrict__ ea,
                        int* __restrict__ cntF, int* __restrict__ cnt3, int E) {
    __shared__ int sh3[3];
    if (threadIdx.x < 3) sh3[threadIdx.x] = 0;
    __syncthreads();
    int e = blockIdx.x * blockDim.x + threadIdx.x;
    if (e < E) {
        int dd = ei[E + e];
        int f = ea[2 * e];
        f = f < 0 ? 0 : (f > 2 ? 2 : f);
        atomicAdd(&cntF[dd * 3 + f], 1);
        atomicAdd(&sh3[f], 1);
    }
    __syncthreads();
    if (threadIdx.x < 3) atomicAdd(&cnt3[threadIdx.x], sh3[threadIdx.x]);
}

// block 0: constant edge-attr projections (posc constant: clip(where(pos>MP,pos,MP),0,MP)==MP).
// blocks 1..: bf16 n-major weight copies Bt1[512][128], Bt2[64][256].
__global__ void k_prep_all(const float* __restrict__ pos_table, const float* __restrict__ pos_W,
                           const float* __restrict__ pos_b, const float* __restrict__ flow_emb,
                           const float* __restrict__ We1, const float* __restrict__ We2,
                           const int* __restrict__ cnt3,
                           float* __restrict__ eaW1, float* __restrict__ loopW1,
                           float* __restrict__ eaW2, float* __restrict__ loopW2,
                           const float* __restrict__ Wl1, const float* __restrict__ Wr1,
                           const float* __restrict__ Wl2, const float* __restrict__ Wr2,
                           unsigned short* __restrict__ Bt1, unsigned short* __restrict__ Bt2,
                           int E) {
    if (blockIdx.x != 0) {
        int i = (blockIdx.x - 1) * 256 + threadIdx.x;
        if (i < 512 * 128) {
            int nn = i >> 7, k = i & 127;
            float v = (nn < 256) ? Wl1[(size_t)k * 256 + nn] : Wr1[(size_t)k * 256 + nn - 256];
            Bt1[i] = bf16r(v);
        } else {
            int j = i - 512 * 128;
            if (j < 64 * 256) {
                int nn = j >> 8, k = j & 255;
                float v = (nn < 32) ? Wl2[(size_t)k * 32 + nn] : Wr2[(size_t)k * 32 + nn - 32];
                Bt2[j] = bf16r(v);
            }
        }
        return;
    }
    __shared__ float posc[128];
    __shared__ float lv[128];
    int t = threadIdx.x;
    if (t < 128) {
        const float* row = pos_table + 5120 * 128;
        float a = pos_b[t];
        for (int k = 0; k < 128; ++k) a += row[k] * pos_W[k * 128 + t];
        posc[t] = a;
        float invE = 1.0f / (float)E;
        lv[t] = ((float)cnt3[0] * flow_emb[t] + (float)cnt3[1] * flow_emb[128 + t] +
                 (float)cnt3[2] * flow_emb[256 + t]) * invE + a;
    }
    __syncthreads();
    {   // layer 1 projections, j = 0..255
        int j = t;
        float a0 = 0.f, a1 = 0.f, a2 = 0.f, al = 0.f;
        for (int k = 0; k < 128; ++k) {
            float w = We1[k * 256 + j];
            float pc = posc[k];
            a0 += (flow_emb[k] + pc) * w;
            a1 += (flow_emb[128 + k] + pc) * w;
            a2 += (flow_emb[256 + k] + pc) * w;
            al += lv[k] * w;
        }
        eaW1[j] = a0; eaW1[256 + j] = a1; eaW1[512 + j] = a2; loopW1[j] = al;
    }
    if (t < 32) {  // layer 2 projections
        int j = t;
        float a0 = 0.f, a1 = 0.f, a2 = 0.f, al = 0.f;
        for (int k = 0; k < 128; ++k) {
            float w = We2[k * 32 + j];
            float pc = posc[k];
            a0 += (flow_emb[k] + pc) * w;
            a1 += (flow_emb[128 + k] + pc) * w;
            a2 += (flow_emb[256 + k] + pc) * w;
            al += lv[k] * w;
        }
        eaW2[j] = a0; eaW2[32 + j] = a1; eaW2[64 + j] = a2; loopW2[j] = al;
    }
}

// ---------- CSR over 3N (dst,flow) keys ----------
__global__ __launch_bounds__(256) void k_scan_block(const int* __restrict__ cnt,
                                                    int* __restrict__ rowptr,
                                                    int* __restrict__ bsum, int n) {
    __shared__ int sh[256];
    int b = blockIdx.x, t = threadIdx.x;
    int base = b * 1024 + t * 4;
    int v0 = base + 0 < n ? cnt[base + 0] : 0;
    int v1 = base + 1 < n ? cnt[base + 1] : 0;
    int v2 = base + 2 < n ? cnt[base + 2] : 0;
    int v3 = base + 3 < n ? cnt[base + 3] : 0;
    int tot = v0 + v1 + v2 + v3;
    sh[t] = tot;
    __syncthreads();
    for (int off = 1; off < 256; off <<= 1) {
        int x = (t >= off) ? sh[t - off] : 0;
        __syncthreads();
        sh[t] += x;
        __syncthreads();
    }
    int excl = (t > 0) ? sh[t - 1] : 0;
    if (base + 0 < n) rowptr[base + 0] = excl;
    if (base + 1 < n) rowptr[base + 1] = excl + v0;
    if (base + 2 < n) rowptr[base + 2] = excl + v0 + v1;
    if (base + 3 < n) rowptr[base + 3] = excl + v0 + v1 + v2;
    if (t == 255) bsum[b] = sh[255];
}

__global__ void k_scan_top(int* __restrict__ bsum, int* __restrict__ rowptr, int nb, int n) {
    if (threadIdx.x == 0 && blockIdx.x == 0) {
        int run = 0;
        for (int b = 0; b < nb; ++b) { int x = bsum[b]; bsum[b] = run; run += x; }
        rowptr[n] = run;
    }
}

__global__ void k_scan_add(int* __restrict__ rowptr, const int* __restrict__ bsum,
                           int* __restrict__ wptr, int n) {
    int i = blockIdx.x * blockDim.x + threadIdx.x;
    if (i < n) {
        int v = rowptr[i] + bsum[i >> 10];
        rowptr[i] = v;
        wptr[i] = v;
    }
}

// scatter src ids into (dst,flow)-sorted order
__global__ void k_scatter(const int* __restrict__ ei, const int* __restrict__ ea,
                          int* __restrict__ wptr, int* __restrict__ packed, int E) {
    int e = blockIdx.x * blockDim.x + threadIdx.x;
    if (e >= E) return;
    int s = ei[e], dd = ei[E + e];
    int f = ea[2 * e];
    f = f < 0 ? 0 : (f > 2 ? 2 : f);
    int p = atomicAdd(&wptr[dd * 3 + f], 1);
    packed[p] = s;
}

// ---------- GEMM 1 (MFMA): xc[N][512] = [h @ Wl+bl | h @ Wr+br], bf16 ----------
__global__ __launch_bounds__(256) void k_gemm1(const int* __restrict__ x,
        const float* __restrict__ text_emb, const float* __restrict__ type_emb,
        const unsigned short* __restrict__ Bt,  // [512][128] bf16, n-major
        const float* __restrict__ bl, const float* __restrict__ br,
        unsigned short* __restrict__ xc, int n) {
    __shared__ unsigned short Ash[64][136];
    __shared__ unsigned short Bsh[128][136];
    int t = threadIdx.x;
    int node0 = blockIdx.x * 64;
    for (int i = t; i < 64 * 128; i += 256) {
        int r = i >> 7, cc = i & 127;
        int nd = node0 + r;
        float v = 0.f;
        if (nd < n)
            v = (cc < 64) ? text_emb[(size_t)x[nd * 2] * 64 + cc]
                          : type_emb[(size_t)x[nd * 2 + 1] * 64 + (cc - 64)];
        Ash[r][cc] = bf16r(v);
    }
    int wave = t >> 6, lane = t & 63;
    int m = lane & 15, q = lane >> 4;
    for (int nb = 0; nb < 4; ++nb) {
        __syncthreads();
        for (int i = t; i < 128 * 16; i += 256) {
            int r = i >> 4, cs = i & 15;
            uint4 v = ((const uint4*)(Bt + (size_t)(nb * 128 + r) * 128))[cs];
            *(uint4*)&Bsh[r][cs * 8] = v;
        }
        __syncthreads();
        f32x4 acc[8];
#pragma unroll
        for (int nt = 0; nt < 8; ++nt) acc[nt] = (f32x4){0.f, 0.f, 0.f, 0.f};
#pragma unroll
        for (int k = 0; k < 128; k += 32) {
            bf16x8 a = *(const bf16x8*)&Ash[wave * 16 + m][k + q * 8];
#pragma unroll
            for (int nt = 0; nt < 8; ++nt) {
                bf16x8 b = *(const bf16x8*)&Bsh[nt * 16 + m][k + q * 8];
                acc[nt] = __builtin_amdgcn_mfma_f32_16x16x32_bf16(a, b, acc[nt], 0, 0, 0);
            }
        }
#pragma unroll
        for (int r = 0; r < 4; ++r) {
            int node = node0 + wave * 16 + q * 4 + r;
            if (node < n) {
                unsigned short* rowp = xc + (size_t)node * 512 + nb * 128 + m;
#pragma unroll
                for (int nt = 0; nt < 8; ++nt) {
                    int ng = nb * 128 + nt * 16 + m;
                    float bv = (ng < 256) ? bl[ng] : br[ng - 256];
                    rowp[nt * 16] = bf16r(acc[nt][r] + bv);
                }
            }
        }
    }
}

// ---------- GEMM 2 (MFMA): xc2[N][64] = [h2 @ Wl+bl | h2 @ Wr+br], bf16 ----------
__global__ __launch_bounds__(256) void k_gemm2(const unsigned short* __restrict__ h2b,
        const unsigned short* __restrict__ Bt,  // [64][256] bf16, n-major
        const float* __restrict__ bl, const float* __restrict__ br,
        unsigned short* __restrict__ xc, int n) {
    __shared__ unsigned short Ash[32][264];
    __shared__ unsigned short Bsh[64][264];
    int t = threadIdx.x;
    int node0 = blockIdx.x * 32;
    for (int i = t; i < 32 * 32; i += 256) {
        int r = i >> 5, cs = i & 31;
        int nd = node0 + r;
        uint4 v = make_uint4(0u, 0u, 0u, 0u);
        if (nd < n) v = ((const uint4*)(h2b + (size_t)nd * 256))[cs];
        *(uint4*)&Ash[r][cs * 8] = v;
    }
    for (int i = t; i < 64 * 32; i += 256) {
        int r = i >> 5, cs = i & 31;
        uint4 v = ((const uint4*)(Bt + (size_t)r * 256))[cs];
        *(uint4*)&Bsh[r][cs * 8] = v;
    }
    __syncthreads();
    int wave = t >> 6, lane = t & 63;
    int m = lane & 15, q = lane >> 4;
    int mrow = (wave >> 1) * 16;
    int nh   = (wave & 1) * 32;
    f32x4 acc[2];
    acc[0] = (f32x4){0.f, 0.f, 0.f, 0.f};
    acc[1] = (f32x4){0.f, 0.f, 0.f, 0.f};
#pragma unroll
    for (int k = 0; k < 256; k += 32) {
        bf16x8 a = *(const bf16x8*)&Ash[mrow + m][k + q * 8];
#pragma unroll
        for (int nt = 0; nt < 2; ++nt) {
            bf16x8 b = *(const bf16x8*)&Bsh[nh + nt * 16 + m][k + q * 8];
            acc[nt] = __builtin_amdgcn_mfma_f32_16x16x32_bf16(a, b, acc[nt], 0, 0, 0);
        }
    }
#pragma unroll
    for (int r = 0; r < 4; ++r) {
        int node = node0 + mrow + q * 4 + r;
        if (node < n) {
#pragma unroll
            for (int nt = 0; nt < 2; ++nt) {
                int ng = nh + nt * 16 + m;
                float bv = (ng < 32) ? bl[ng] : br[ng - 32];
                xc[(size_t)node * 64 + ng] = bf16r(acc[nt][r] + bv);
            }
        }
    }
}

// ---------- GAT layer 1: one wave per dst, 4 dims/lane, 4 edges in flight ----------
// Flow-sorted CSR: 3 runs per dst, flow vector loop-constant (no selects).
__global__ __launch_bounds__(256) void k_gat256(const unsigned short* __restrict__ xc1,
        const int* __restrict__ rowptrF, const int* __restrict__ packed,
        const float* __restrict__ eaW, const float* __restrict__ loopW,
        const float* __restrict__ att, const float* __restrict__ bias,
        unsigned short* __restrict__ h2b, int n) {
    int wid = (blockIdx.x * blockDim.x + threadIdx.x) >> 6;
    int lane = threadIdx.x & 63;
    if (wid >= n) return;
    int d = wid;
    int c = lane * 4;
    float4 xld = bf16x4_to_f4(((const uint2*)(xc1 + (size_t)d * 512))[lane]);
    float4 xrd = bf16x4_to_f4(((const uint2*)(xc1 + (size_t)d * 512 + 256))[lane]);
    float4 av = *(const float4*)(att + c);
    float4 av6, av4;
    av6.x = 0.6f * av.x; av6.y = 0.6f * av.y; av6.z = 0.6f * av.z; av6.w = 0.6f * av.w;
    av4.x = 0.4f * av.x; av4.y = 0.4f * av.y; av4.z = 0.4f * av.z; av4.w = 0.4f * av.w;
    // self loop
    float den, wself;
    float4 acc;
    {
        float4 lw = *(const float4*)(loopW + c);
        lw.x += xrd.x; lw.y += xrd.y; lw.z += xrd.z; lw.w += xrd.w;
        float q = wsum64(sdot4(xld, lw, av6, av4));
        wself = __expf(q);
        den = wself;
        acc.x = wself * xld.x; acc.y = wself * xld.y;
        acc.z = wself * xld.z; acc.w = wself * xld.w;
    }
#pragma unroll 1
    for (int f = 0; f < 3; ++f) {
        float4 pre = *(const float4*)(eaW + f * 256 + c);
        pre.x += xrd.x; pre.y += xrd.y; pre.z += xrd.z; pre.w += xrd.w;
        int p = rowptrF[d * 3 + f], p1 = rowptrF[d * 3 + f + 1];
        for (; p + 4 <= p1; p += 4) {
            int s0 = packed[p],     s1 = packed[p + 1];
            int s2 = packed[p + 2], s3 = packed[p + 3];
            uint2 u0 = ((const uint2*)(xc1 + (size_t)s0 * 512))[lane];
            uint2 u1 = ((const uint2*)(xc1 + (size_t)s1 * 512))[lane];
            uint2 u2 = ((const uint2*)(xc1 + (size_t)s2 * 512))[lane];
            uint2 u3 = ((const uint2*)(xc1 + (size_t)s3 * 512))[lane];
            float4 xs0 = bf16x4_to_f4(u0);
            float4 xs1 = bf16x4_to_f4(u1);
            float4 xs2 = bf16x4_to_f4(u2);
            float4 xs3 = bf16x4_to_f4(u3);
            float q0 = sdot4(xs0, pre, av6, av4);
            float q1 = sdot4(xs1, pre, av6, av4);
            float q2 = sdot4(xs2, pre, av6, av4);
            float q3 = sdot4(xs3, pre, av6, av4);
#pragma unroll
            for (int off = 32; off >= 1; off >>= 1) {
                q0 += __shfl_xor(q0, off, 64);
                q1 += __shfl_xor(q1, off, 64);
                q2 += __shfl_xor(q2, off, 64);
                q3 += __shfl_xor(q3, off, 64);
            }
            float w0 = __expf(q0), w1 = __expf(q1);
            float w2 = __expf(q2), w3 = __expf(q3);
            den += (w0 + w1) + (w2 + w3);
            acc.x += w0 * xs0.x + w1 * xs1.x + w2 * xs2.x + w3 * xs3.x;
            acc.y += w0 * xs0.y + w1 * xs1.y + w2 * xs2.y + w3 * xs3.y;
            acc.z += w0 * xs0.z + w1 * xs1.z + w2 * xs2.z + w3 * xs3.z;
            acc.w += w0 * xs0.w + w1 * xs1.w + w2 * xs2.w + w3 * xs3.w;
        }
        for (; p < p1; ++p) {
            int s = packed[p];
            float4 xs = bf16x4_to_f4(((const uint2*)(xc1 + (size_t)s * 512))[lane]);
            float qq = wsum64(sdot4(xs, pre, av6, av4));
            float w = __expf(qq);
            den += w;
            acc.x += w * xs.x; acc.y += w * xs.y; acc.z += w * xs.z; acc.w += w * xs.w;
        }
    }
    float inv = 1.f / den;
    float4 bv = *(const float4*)(bias + c);
    float ox = fmaf(acc.x, inv, bv.x), oy = fmaf(acc.y, inv, bv.y);
    float oz = fmaf(acc.z, inv, bv.z), ow = fmaf(acc.w, inv, bv.w);
    ((uint2*)(h2b + (size_t)d * 256))[lane] = make_uint2(bf16pack(ox, oy), bf16pack(oz, ow));
}

// ---------- GAT layer 2: wave per dst, 4 groups x 16 lanes x 2 dims/lane ----------
__global__ __launch_bounds__(256) void k_gat32(const unsigned short* __restrict__ xc2,
        const int* __restrict__ rowptrF, const int* __restrict__ packed,
        const float* __restrict__ eaW, const float* __restrict__ loopW,
        const float* __restrict__ att, const float* __restrict__ bias,
        float* __restrict__ out, int n) {
    int wid = (blockIdx.x * blockDim.x + threadIdx.x) >> 6;
    if (wid >= n) return;
    int lane = threadIdx.x & 63;
    int g = lane >> 4, li = lane & 15;
    int d = wid;
    unsigned int uxl = ((const unsigned int*)(xc2 + (size_t)d * 64))[li];
    unsigned int uxr = ((const unsigned int*)(xc2 + (size_t)d * 64 + 32))[li];
    float xl0 = __uint_as_float(uxl << 16), xl1 = __uint_as_float(uxl & 0xFFFF0000u);
    float xr0 = __uint_as_float(uxr << 16), xr1 = __uint_as_float(uxr & 0xFFFF0000u);
    float2 avv = ((const float2*)att)[li];
    float a60 = 0.6f * avv.x, a61 = 0.6f * avv.y;
    float a40 = 0.4f * avv.x, a41 = 0.4f * avv.y;
    float den, acc0, acc1;
    {
        float2 lwv = ((const float2*)loopW)[li];
        float m0 = xl0 + xr0 + lwv.x, m1 = xl1 + xr1 + lwv.y;
        float q = a60 * m0 + a40 * fabsf(m0);
        q = fmaf(a61, m1, q); q = fmaf(a41, fabsf(m1), q);
        q += __shfl_xor(q, 1, 64); q += __shfl_xor(q, 2, 64);
        q += __shfl_xor(q, 4, 64); q += __shfl_xor(q, 8, 64);
        float wself = __expf(q);
        den  = (g == 0) ? wself : 0.f;
        acc0 = (g == 0) ? wself * xl0 : 0.f;
        acc1 = (g == 0) ? wself * xl1 : 0.f;
    }
#pragma unroll 1
    for (int f = 0; f < 3; ++f) {
        float2 ev = ((const float2*)(eaW + f * 32))[li];
        float pre0 = ev.x + xr0, pre1 = ev.y + xr1;
        int pA = rowptrF[d * 3 + f], pB = rowptrF[d * 3 + f + 1];
        int p = pA + g;
        for (; p + 4 < pB; p += 8) {   // 2 edges in flight per group (8 per wave)
            int s0 = packed[p], s1 = packed[p + 4];
            unsigned int ua = ((const unsigned int*)(xc2 + (size_t)s0 * 64))[li];
            unsigned int ub = ((const unsigned int*)(xc2 + (size_t)s1 * 64))[li];
            float xa0 = __uint_as_float(ua << 16), xa1 = __uint_as_float(ua & 0xFFFF0000u);
            float xb0 = __uint_as_float(ub << 16), xb1 = __uint_as_float(ub & 0xFFFF0000u);
            float ma0 = xa0 + pre0, ma1 = xa1 + pre1;
            float mb0 = xb0 + pre0, mb1 = xb1 + pre1;
            float qa = a60 * ma0 + a40 * fabsf(ma0);
            qa = fmaf(a61, ma1, qa); qa = fmaf(a41, fabsf(ma1), qa);
            float qb = a60 * mb0 + a40 * fabsf(mb0);
            qb = fmaf(a61, mb1, qb); qb = fmaf(a41, fabsf(mb1), qb);
#pragma unroll
            for (int off = 1; off <= 8; off <<= 1) {
                qa += __shfl_xor(qa, off, 64);
                qb += __shfl_xor(qb, off, 64);
            }
            float wa = __expf(qa), wb = __expf(qb);
            den += wa + wb;
            acc0 = fmaf(wb, xb0, fmaf(wa, xa0, acc0));
            acc1 = fmaf(wb, xb1, fmaf(wa, xa1, acc1));
        }
        for (; p < pB; p += 4) {
            int s = packed[p];
            unsigned int u = ((const unsigned int*)(xc2 + (size_t)s * 64))[li];
            float x0 = __uint_as_float(u << 16), x1 = __uint_as_float(u & 0xFFFF0000u);
            float m0 = x0 + pre0, m1 = x1 + pre1;
            float q = a60 * m0 + a40 * fabsf(m0);
            q = fmaf(a61, m1, q); q = fmaf(a41, fabsf(m1), q);
            q += __shfl_xor(q, 1, 64); q += __shfl_xor(q, 2, 64);
            q += __shfl_xor(q, 4, 64); q += __shfl_xor(q, 8, 64);
            float w = __expf(q);
            den += w;
            acc0 = fmaf(w, x0, acc0);
            acc1 = fmaf(w, x1, acc1);
        }
    }
    // combine the 4 groups
    acc0 += __shfl_xor(acc0, 16, 64); acc0 += __shfl_xor(acc0, 32, 64);
    acc1 += __shfl_xor(acc1, 16, 64); acc1 += __shfl_xor(acc1, 32, 64);
    den  += __shfl_xor(den, 16, 64);  den  += __shfl_xor(den, 32, 64);
    if (g == 0) {
        float2 bvv = ((const float2*)bias)[li];
        float inv = 1.f / den;
        float2 o;
        o.x = fmaf(acc0, inv, bvv.x);
        o.y = fmaf(acc1, inv, bvv.y);
        ((float2*)(out + (size_t)d * 32))[li] = o;
    }
}

// ---------- mean over nodes + policy head ----------
__global__ __launch_bounds__(256) void k_mean(const float* __restrict__ out2,
                                              float* __restrict__ gsum, int n) {
    __shared__ float sh[256];
    int t = threadIdx.x;
    int c = t & 31, g = t >> 5;
    float acc = 0.f;
    for (int nd = blockIdx.x * 8 + g; nd < n; nd += gridDim.x * 8)
        acc += out2[(size_t)nd * 32 + c];
    sh[t] = acc;
    __syncthreads();
    if (t < 32) {
        float s2 = 0.f;
#pragma unroll
        for (int gg = 0; gg < 8; ++gg) s2 += sh[gg * 32 + c];
        atomicAdd(&gsum[c], s2);
    }
}

__global__ void k_final(const float* __restrict__ gsum, const float* __restrict__ policy_W,
                        const float* __restrict__ policy_b, float* __restrict__ out, int n) {
    int t = threadIdx.x;  // 0..63 — one wave
    float invN = 1.0f / (float)n;
    float acc = policy_b[t];
    for (int cc = 0; cc < 32; ++cc) acc += gsum[cc] * invN * policy_W[cc * 64 + t];
    float mx = wmax64(acc);
    float ex = __expf(acc - mx);
    float s = wsum64(ex);
    out[t] = ex / s;
}

extern "C" void kernel_launch(void* const* d_in, const int* in_sizes, int n_in,
                              void* d_out, int out_size, void* d_ws, size_t ws_size,
                              hipStream_t stream) {
    const int* x          = (const int*)d_in[0];
    const int* edge_index = (const int*)d_in[1];
    const int* edge_attr  = (const int*)d_in[2];
    const float* text_emb = (const float*)d_in[3];
    const float* type_emb = (const float*)d_in[4];
    const float* flow_emb = (const float*)d_in[5];
    const float* pos_table= (const float*)d_in[6];
    const float* pos_W    = (const float*)d_in[7];
    const float* pos_b    = (const float*)d_in[8];
    const float* c1_Wl    = (const float*)d_in[9];
    const float* c1_bl    = (const float*)d_in[10];
    const float* c1_Wr    = (const float*)d_in[11];
    const float* c1_br    = (const float*)d_in[12];
    const float* c1_We    = (const float*)d_in[13];
    const float* c1_att   = (const float*)d_in[14];
    const float* c1_bias  = (const float*)d_in[15];
    const float* c2_Wl    = (const float*)d_in[16];
    const float* c2_bl    = (const float*)d_in[17];
    const float* c2_Wr    = (const float*)d_in[18];
    const float* c2_br    = (const float*)d_in[19];
    const float* c2_We    = (const float*)d_in[20];
    const float* c2_att   = (const float*)d_in[21];
    const float* c2_bias  = (const float*)d_in[22];
    const float* policy_W = (const float*)d_in[23];
    const float* policy_b = (const float*)d_in[24];
    float* out = (float*)d_out;

    const int N = in_sizes[0] / 2;   // 50000
    const int E = in_sizes[1] / 2;   // 800000
    const int n3 = 3 * N;

    // ---- workspace layout (256B-aligned chunks) ----
    char* base = (char*)d_ws;
    size_t off = 0;
    auto alloc = [&](size_t bytes) -> void* {
        void* p = base + off;
        off = (off + bytes + 255) & ~(size_t)255;
        return p;
    };
    unsigned short* xc1  = (unsigned short*)alloc((size_t)N * 512 * 2);  // xl1|xr1 bf16
    unsigned short* h2b  = (unsigned short*)alloc((size_t)N * 256 * 2);  // h2 bf16
    unsigned short* xc2  = (unsigned short*)alloc((size_t)N * 64 * 2);   // xl2|xr2 bf16
    float*          out2 = (float*)alloc((size_t)N * 32 * 4);
    unsigned short* Bt1  = (unsigned short*)alloc((size_t)512 * 128 * 2);
    unsigned short* Bt2  = (unsigned short*)alloc((size_t)64 * 256 * 2);
    // contiguous zero-region: cntF (3N) | cnt3 (4) | gsum (32)
    int*            zreg   = (int*)alloc((size_t)(n3 + 36) * 4);
    int*            cntF   = zreg;
    int*            cnt3   = zreg + n3;
    float*          gsum   = (float*)(zreg + n3 + 4);
    int*            rowptrF= (int*)alloc((size_t)(n3 + 1) * 4);
    int*            packed = (int*)alloc((size_t)E * 4);
    int*            bsum   = (int*)alloc(256 * 4);
    float*          eaW1   = (float*)alloc(768 * 4);
    float*          loopW1 = (float*)alloc(256 * 4);
    float*          eaW2   = (float*)alloc(96 * 4);
    float*          loopW2 = (float*)alloc(32 * 4);

    // ---- init (ws is poisoned 0xAA every call) ----
    hipMemsetAsync(zreg, 0, (size_t)(n3 + 36) * 4, stream);

    // ---- (dst,flow) histogram + flow counts; tables + weight conversion ----
    k_edges<<<(E + 255) / 256, 256, 0, stream>>>(edge_index, edge_attr, cntF, cnt3, E);
    k_prep_all<<<1 + (512 * 128 + 64 * 256) / 256, 256, 0, stream>>>(
        pos_table, pos_W, pos_b, flow_emb, c1_We, c2_We, cnt3,
        eaW1, loopW1, eaW2, loopW2, c1_Wl, c1_Wr, c2_Wl, c2_Wr, Bt1, Bt2, E);

    // ---- CSR build over 3N keys ((dst,flow)-sorted edge list) ----
    int nb = (n3 + 1023) / 1024;
    k_scan_block<<<nb, 256, 0, stream>>>(cntF, rowptrF, bsum, n3);
    k_scan_top<<<1, 64, 0, stream>>>(bsum, rowptrF, nb, n3);
    k_scan_add<<<(n3 + 255) / 256, 256, 0, stream>>>(rowptrF, bsum, cntF, n3);
    k_scatter<<<(E + 255) / 256, 256, 0, stream>>>(edge_index, edge_attr, cntF, packed, E);

    // ---- layer 1 ----
    k_gemm1<<<(N + 63) / 64, 256, 0, stream>>>(x, text_emb, type_emb, Bt1,
                                               c1_bl, c1_br, xc1, N);
    k_gat256<<<(N + 3) / 4, 256, 0, stream>>>(xc1, rowptrF, packed, eaW1, loopW1,
                                              c1_att, c1_bias, h2b, N);

    // ---- layer 2 ----
    k_gemm2<<<(N + 31) / 32, 256, 0, stream>>>(h2b, Bt2, c2_bl, c2_br, xc2, N);
    k_gat32<<<(N + 3) / 4, 256, 0, stream>>>(xc2, rowptrF, packed, eaW2, loopW2,
                                             c2_att, c2_bias, out2, N);

    // ---- readout ----
    k_mean<<<256, 256, 0, stream>>>(out2, gsum, N);
    k_final<<<1, 64, 0, stream>>>(gsum, policy_W, policy_b, out, N);
}

// Round 7
// 431.612 us; speedup vs baseline: 1.1919x; 1.0894x over previous
//
#include <hip/hip_runtime.h>

#define NEG_SLOPE 0.2f

typedef __attribute__((ext_vector_type(8))) short bf16x8;
typedef __attribute__((ext_vector_type(4))) float f32x4;

static __device__ __forceinline__ float wsum64(float v) {
#pragma unroll
    for (int off = 32; off >= 1; off >>= 1) v += __shfl_xor(v, off, 64);
    return v;
}
static __device__ __forceinline__ float wmax64(float v) {
#pragma unroll
    for (int off = 32; off >= 1; off >>= 1) v = fmaxf(v, __shfl_xor(v, off, 64));
    return v;
}

// fp32 -> bf16 (RNE)
static __device__ __forceinline__ unsigned short bf16r(float a) {
    unsigned int u = __float_as_uint(a);
    return (unsigned short)((u + 0x7FFFu + ((u >> 16) & 1u)) >> 16);
}
static __device__ __forceinline__ unsigned int bf16pack(float a, float b) {
    unsigned int ua = __float_as_uint(a);
    ua = (ua + 0x7FFFu + ((ua >> 16) & 1u)) >> 16;
    unsigned int ub = __float_as_uint(b);
    ub = (ub + 0x7FFFu + ((ub >> 16) & 1u)) & 0xFFFF0000u;
    return ua | ub;
}
// expand 4 bf16 (uint2) -> float4
static __device__ __forceinline__ float4 bf16x4_to_f4(uint2 u) {
    float4 v;
    v.x = __uint_as_float(u.x << 16);
    v.y = __uint_as_float(u.x & 0xFFFF0000u);
    v.z = __uint_as_float(u.y << 16);
    v.w = __uint_as_float(u.y & 0xFFFF0000u);
    return v;
}

// score partial: sum_i 0.6*av_i*m_i + 0.4*av_i*|m_i|  (leaky-relu folded; abs free)
static __device__ __forceinline__ float sdot4(const float4 xs, const float4 pre,
                                              const float4 av6, const float4 av4) {
    float m0 = xs.x + pre.x, m1 = xs.y + pre.y;
    float m2 = xs.z + pre.z, m3 = xs.w + pre.w;
    float q = av6.x * m0 + av4.x * fabsf(m0);
    q = fmaf(av6.y, m1, q); q = fmaf(av4.y, fabsf(m1), q);
    q = fmaf(av6.z, m2, q); q = fmaf(av4.z, fabsf(m2), q);
    q = fmaf(av6.w, m3, q); q = fmaf(av4.w, fabsf(m3), q);
    return q;
}

// fused: (dst,flow) histogram + global flow counts
__global__ void k_edges(const int* __restrict__ ei, const int* __restrict__ ea,
                        int* __restrict__ cntF, int* __restrict__ cnt3, int E) {
    __shared__ int sh3[3];
    if (threadIdx.x < 3) sh3[threadIdx.x] = 0;
    __syncthreads();
    int e = blockIdx.x * blockDim.x + threadIdx.x;
    if (e < E) {
        int dd = ei[E + e];
        int f = ea[2 * e];
        f = f < 0 ? 0 : (f > 2 ? 2 : f);
        atomicAdd(&cntF[dd * 3 + f], 1);
        atomicAdd(&sh3[f], 1);
    }
    __syncthreads();
    if (threadIdx.x < 3) atomicAdd(&cnt3[threadIdx.x], sh3[threadIdx.x]);
}

// block 0: constant edge-attr projections (posc constant: clip(where(pos>MP,pos,MP),0,MP)==MP).
// blocks 1..: bf16 n-major weight copies Bt1[512][128], Bt2[64][256].
__global__ void k_prep_all(const float* __restrict__ pos_table, const float* __restrict__ pos_W,
                           const float* __restrict__ pos_b, const float* __restrict__ flow_emb,
                           const float* __restrict__ We1, const float* __restrict__ We2,
                           const int* __restrict__ cnt3,
                           float* __restrict__ eaW1, float* __restrict__ loopW1,
                           float* __restrict__ eaW2, float* __restrict__ loopW2,
                           const float* __restrict__ Wl1, const float* __restrict__ Wr1,
                           const float* __restrict__ Wl2, const float* __restrict__ Wr2,
                           unsigned short* __restrict__ Bt1, unsigned short* __restrict__ Bt2,
                           int E) {
    if (blockIdx.x != 0) {
        int i = (blockIdx.x - 1) * 256 + threadIdx.x;
        if (i < 512 * 128) {
            int nn = i >> 7, k = i & 127;
            float v = (nn < 256) ? Wl1[(size_t)k * 256 + nn] : Wr1[(size_t)k * 256 + nn - 256];
            Bt1[i] = bf16r(v);
        } else {
            int j = i - 512 * 128;
            if (j < 64 * 256) {
                int nn = j >> 8, k = j & 255;
                float v = (nn < 32) ? Wl2[(size_t)k * 32 + nn] : Wr2[(size_t)k * 32 + nn - 32];
                Bt2[j] = bf16r(v);
            }
        }
        return;
    }
    __shared__ float posc[128];
    __shared__ float lv[128];
    int t = threadIdx.x;
    if (t < 128) {
        const float* row = pos_table + 5120 * 128;
        float a = pos_b[t];
        for (int k = 0; k < 128; ++k) a += row[k] * pos_W[k * 128 + t];
        posc[t] = a;
        float invE = 1.0f / (float)E;
        lv[t] = ((float)cnt3[0] * flow_emb[t] + (float)cnt3[1] * flow_emb[128 + t] +
                 (float)cnt3[2] * flow_emb[256 + t]) * invE + a;
    }
    __syncthreads();
    {   // layer 1 projections, j = 0..255
        int j = t;
        float a0 = 0.f, a1 = 0.f, a2 = 0.f, al = 0.f;
        for (int k = 0; k < 128; ++k) {
            float w = We1[k * 256 + j];
            float pc = posc[k];
            a0 += (flow_emb[k] + pc) * w;
            a1 += (flow_emb[128 + k] + pc) * w;
            a2 += (flow_emb[256 + k] + pc) * w;
            al += lv[k] * w;
        }
        eaW1[j] = a0; eaW1[256 + j] = a1; eaW1[512 + j] = a2; loopW1[j] = al;
    }
    if (t < 32) {  // layer 2 projections
        int j = t;
        float a0 = 0.f, a1 = 0.f, a2 = 0.f, al = 0.f;
        for (int k = 0; k < 128; ++k) {
            float w = We2[k * 32 + j];
            float pc = posc[k];
            a0 += (flow_emb[k] + pc) * w;
            a1 += (flow_emb[128 + k] + pc) * w;
            a2 += (flow_emb[256 + k] + pc) * w;
            al += lv[k] * w;
        }
        eaW2[j] = a0; eaW2[32 + j] = a1; eaW2[64 + j] = a2; loopW2[j] = al;
    }
}

// ---------- CSR over 3N (dst,flow) keys ----------
__global__ __launch_bounds__(256) void k_scan_block(const int* __restrict__ cnt,
                                                    int* __restrict__ rowptr,
                                                    int* __restrict__ bsum, int n) {
    __shared__ int sh[256];
    int b = blockIdx.x, t = threadIdx.x;
    int base = b * 1024 + t * 4;
    int v0 = base + 0 < n ? cnt[base + 0] : 0;
    int v1 = base + 1 < n ? cnt[base + 1] : 0;
    int v2 = base + 2 < n ? cnt[base + 2] : 0;
    int v3 = base + 3 < n ? cnt[base + 3] : 0;
    int tot = v0 + v1 + v2 + v3;
    sh[t] = tot;
    __syncthreads();
    for (int off = 1; off < 256; off <<= 1) {
        int x = (t >= off) ? sh[t - off] : 0;
        __syncthreads();
        sh[t] += x;
        __syncthreads();
    }
    int excl = (t > 0) ? sh[t - 1] : 0;
    if (base + 0 < n) rowptr[base + 0] = excl;
    if (base + 1 < n) rowptr[base + 1] = excl + v0;
    if (base + 2 < n) rowptr[base + 2] = excl + v0 + v1;
    if (base + 3 < n) rowptr[base + 3] = excl + v0 + v1 + v2;
    if (t == 255) bsum[b] = sh[255];
}

__global__ void k_scan_top(int* __restrict__ bsum, int* __restrict__ rowptr, int nb, int n) {
    if (threadIdx.x == 0 && blockIdx.x == 0) {
        int run = 0;
        for (int b = 0; b < nb; ++b) { int x = bsum[b]; bsum[b] = run; run += x; }
        rowptr[n] = run;
    }
}

__global__ void k_scan_add(int* __restrict__ rowptr, const int* __restrict__ bsum,
                           int* __restrict__ wptr, int n) {
    int i = blockIdx.x * blockDim.x + threadIdx.x;
    if (i < n) {
        int v = rowptr[i] + bsum[i >> 10];
        rowptr[i] = v;
        wptr[i] = v;
    }
}

// scatter src|flow<<16 into (dst,flow)-sorted order
__global__ void k_scatter(const int* __restrict__ ei, const int* __restrict__ ea,
                          int* __restrict__ wptr, int* __restrict__ packed, int E) {
    int e = blockIdx.x * blockDim.x + threadIdx.x;
    if (e >= E) return;
    int s = ei[e], dd = ei[E + e];
    int f = ea[2 * e];
    f = f < 0 ? 0 : (f > 2 ? 2 : f);
    int p = atomicAdd(&wptr[dd * 3 + f], 1);
    packed[p] = s | (f << 16);
}

// ---------- GEMM 1 (MFMA): xc[N][512] = [h @ Wl+bl | h @ Wr+br], bf16 ----------
__global__ __launch_bounds__(256) void k_gemm1(const int* __restrict__ x,
        const float* __restrict__ text_emb, const float* __restrict__ type_emb,
        const unsigned short* __restrict__ Bt,  // [512][128] bf16, n-major
        const float* __restrict__ bl, const float* __restrict__ br,
        unsigned short* __restrict__ xc, int n) {
    __shared__ unsigned short Ash[64][136];
    __shared__ unsigned short Bsh[128][136];
    int t = threadIdx.x;
    int node0 = blockIdx.x * 64;
    for (int i = t; i < 64 * 128; i += 256) {
        int r = i >> 7, cc = i & 127;
        int nd = node0 + r;
        float v = 0.f;
        if (nd < n)
            v = (cc < 64) ? text_emb[(size_t)x[nd * 2] * 64 + cc]
                          : type_emb[(size_t)x[nd * 2 + 1] * 64 + (cc - 64)];
        Ash[r][cc] = bf16r(v);
    }
    int wave = t >> 6, lane = t & 63;
    int m = lane & 15, q = lane >> 4;
    for (int nb = 0; nb < 4; ++nb) {
        __syncthreads();
        for (int i = t; i < 128 * 16; i += 256) {
            int r = i >> 4, cs = i & 15;
            uint4 v = ((const uint4*)(Bt + (size_t)(nb * 128 + r) * 128))[cs];
            *(uint4*)&Bsh[r][cs * 8] = v;
        }
        __syncthreads();
        f32x4 acc[8];
#pragma unroll
        for (int nt = 0; nt < 8; ++nt) acc[nt] = (f32x4){0.f, 0.f, 0.f, 0.f};
#pragma unroll
        for (int k = 0; k < 128; k += 32) {
            bf16x8 a = *(const bf16x8*)&Ash[wave * 16 + m][k + q * 8];
#pragma unroll
            for (int nt = 0; nt < 8; ++nt) {
                bf16x8 b = *(const bf16x8*)&Bsh[nt * 16 + m][k + q * 8];
                acc[nt] = __builtin_amdgcn_mfma_f32_16x16x32_bf16(a, b, acc[nt], 0, 0, 0);
            }
        }
#pragma unroll
        for (int r = 0; r < 4; ++r) {
            int node = node0 + wave * 16 + q * 4 + r;
            if (node < n) {
                unsigned short* rowp = xc + (size_t)node * 512 + nb * 128 + m;
#pragma unroll
                for (int nt = 0; nt < 8; ++nt) {
                    int ng = nb * 128 + nt * 16 + m;
                    float bv = (ng < 256) ? bl[ng] : br[ng - 256];
                    rowp[nt * 16] = bf16r(acc[nt][r] + bv);
                }
            }
        }
    }
}

// ---------- GEMM 2 (MFMA): xc2[N][64] = [h2 @ Wl+bl | h2 @ Wr+br], bf16 ----------
__global__ __launch_bounds__(256) void k_gemm2(const unsigned short* __restrict__ h2b,
        const unsigned short* __restrict__ Bt,  // [64][256] bf16, n-major
        const float* __restrict__ bl, const float* __restrict__ br,
        unsigned short* __restrict__ xc, int n) {
    __shared__ unsigned short Ash[32][264];
    __shared__ unsigned short Bsh[64][264];
    int t = threadIdx.x;
    int node0 = blockIdx.x * 32;
    for (int i = t; i < 32 * 32; i += 256) {
        int r = i >> 5, cs = i & 31;
        int nd = node0 + r;
        uint4 v = make_uint4(0u, 0u, 0u, 0u);
        if (nd < n) v = ((const uint4*)(h2b + (size_t)nd * 256))[cs];
        *(uint4*)&Ash[r][cs * 8] = v;
    }
    for (int i = t; i < 64 * 32; i += 256) {
        int r = i >> 5, cs = i & 31;
        uint4 v = ((const uint4*)(Bt + (size_t)r * 256))[cs];
        *(uint4*)&Bsh[r][cs * 8] = v;
    }
    __syncthreads();
    int wave = t >> 6, lane = t & 63;
    int m = lane & 15, q = lane >> 4;
    int mrow = (wave >> 1) * 16;
    int nh   = (wave & 1) * 32;
    f32x4 acc[2];
    acc[0] = (f32x4){0.f, 0.f, 0.f, 0.f};
    acc[1] = (f32x4){0.f, 0.f, 0.f, 0.f};
#pragma unroll
    for (int k = 0; k < 256; k += 32) {
        bf16x8 a = *(const bf16x8*)&Ash[mrow + m][k + q * 8];
#pragma unroll
        for (int nt = 0; nt < 2; ++nt) {
            bf16x8 b = *(const bf16x8*)&Bsh[nh + nt * 16 + m][k + q * 8];
            acc[nt] = __builtin_amdgcn_mfma_f32_16x16x32_bf16(a, b, acc[nt], 0, 0, 0);
        }
    }
#pragma unroll
    for (int r = 0; r < 4; ++r) {
        int node = node0 + mrow + q * 4 + r;
        if (node < n) {
#pragma unroll
            for (int nt = 0; nt < 2; ++nt) {
                int ng = nh + nt * 16 + m;
                float bv = (ng < 32) ? bl[ng] : br[ng - 32];
                xc[(size_t)node * 64 + ng] = bf16r(acc[nt][r] + bv);
            }
        }
    }
}

// ---------- GAT layer 1: one wave per dst, 4 dims/lane, 4 edges in flight ----------
// Single loop over [rowptrF[3d], rowptrF[3d+3]); flow decoded from packed bits.
__global__ __launch_bounds__(256) void k_gat256(const unsigned short* __restrict__ xc1,
        const int* __restrict__ rowptrF, const int* __restrict__ packed,
        const float* __restrict__ eaW, const float* __restrict__ loopW,
        const float* __restrict__ att, const float* __restrict__ bias,
        unsigned short* __restrict__ h2b, int n) {
    int wid = (blockIdx.x * blockDim.x + threadIdx.x) >> 6;
    int lane = threadIdx.x & 63;
    if (wid >= n) return;
    int d = wid;
    int c = lane * 4;
    float4 xld = bf16x4_to_f4(((const uint2*)(xc1 + (size_t)d * 512))[lane]);
    float4 xrd = bf16x4_to_f4(((const uint2*)(xc1 + (size_t)d * 512 + 256))[lane]);
    float4 av = *(const float4*)(att + c);
    float4 av6, av4;
    av6.x = 0.6f * av.x; av6.y = 0.6f * av.y; av6.z = 0.6f * av.z; av6.w = 0.6f * av.w;
    av4.x = 0.4f * av.x; av4.y = 0.4f * av.y; av4.z = 0.4f * av.z; av4.w = 0.4f * av.w;
    // premixed per-flow vectors r_f = xr[d] + eaW[f]
    float4 r0 = *(const float4*)(eaW + c);
    float4 r1 = *(const float4*)(eaW + 256 + c);
    float4 r2 = *(const float4*)(eaW + 512 + c);
    r0.x += xrd.x; r0.y += xrd.y; r0.z += xrd.z; r0.w += xrd.w;
    r1.x += xrd.x; r1.y += xrd.y; r1.z += xrd.z; r1.w += xrd.w;
    r2.x += xrd.x; r2.y += xrd.y; r2.z += xrd.z; r2.w += xrd.w;
    // self loop
    float den;
    float4 acc;
    {
        float4 lw = *(const float4*)(loopW + c);
        lw.x += xrd.x; lw.y += xrd.y; lw.z += xrd.z; lw.w += xrd.w;
        float q = wsum64(sdot4(xld, lw, av6, av4));
        float wself = __expf(q);
        den = wself;
        acc.x = wself * xld.x; acc.y = wself * xld.y;
        acc.z = wself * xld.z; acc.w = wself * xld.w;
    }
    int p = rowptrF[d * 3], p1 = rowptrF[d * 3 + 3];
    for (; p + 4 <= p1; p += 4) {
        int pk0 = packed[p],     pk1 = packed[p + 1];
        int pk2 = packed[p + 2], pk3 = packed[p + 3];
        uint2 u0 = ((const uint2*)(xc1 + (size_t)(pk0 & 0xFFFF) * 512))[lane];
        uint2 u1 = ((const uint2*)(xc1 + (size_t)(pk1 & 0xFFFF) * 512))[lane];
        uint2 u2 = ((const uint2*)(xc1 + (size_t)(pk2 & 0xFFFF) * 512))[lane];
        uint2 u3 = ((const uint2*)(xc1 + (size_t)(pk3 & 0xFFFF) * 512))[lane];
        float4 xs0 = bf16x4_to_f4(u0);
        float4 xs1 = bf16x4_to_f4(u1);
        float4 xs2 = bf16x4_to_f4(u2);
        float4 xs3 = bf16x4_to_f4(u3);
        int f0 = pk0 >> 16, f1 = pk1 >> 16, f2 = pk2 >> 16, f3 = pk3 >> 16;
        float4 pr0 = (f0 == 0) ? r0 : ((f0 == 1) ? r1 : r2);
        float4 pr1 = (f1 == 0) ? r0 : ((f1 == 1) ? r1 : r2);
        float4 pr2 = (f2 == 0) ? r0 : ((f2 == 1) ? r1 : r2);
        float4 pr3 = (f3 == 0) ? r0 : ((f3 == 1) ? r1 : r2);
        float q0 = sdot4(xs0, pr0, av6, av4);
        float q1 = sdot4(xs1, pr1, av6, av4);
        float q2 = sdot4(xs2, pr2, av6, av4);
        float q3 = sdot4(xs3, pr3, av6, av4);
#pragma unroll
        for (int off = 32; off >= 1; off >>= 1) {
            q0 += __shfl_xor(q0, off, 64);
            q1 += __shfl_xor(q1, off, 64);
            q2 += __shfl_xor(q2, off, 64);
            q3 += __shfl_xor(q3, off, 64);
        }
        float w0 = __expf(q0), w1 = __expf(q1);
        float w2 = __expf(q2), w3 = __expf(q3);
        den += (w0 + w1) + (w2 + w3);
        acc.x += w0 * xs0.x + w1 * xs1.x + w2 * xs2.x + w3 * xs3.x;
        acc.y += w0 * xs0.y + w1 * xs1.y + w2 * xs2.y + w3 * xs3.y;
        acc.z += w0 * xs0.z + w1 * xs1.z + w2 * xs2.z + w3 * xs3.z;
        acc.w += w0 * xs0.w + w1 * xs1.w + w2 * xs2.w + w3 * xs3.w;
    }
    for (; p < p1; ++p) {
        int pk = packed[p];
        float4 xs = bf16x4_to_f4(((const uint2*)(xc1 + (size_t)(pk & 0xFFFF) * 512))[lane]);
        int f = pk >> 16;
        float4 pr = (f == 0) ? r0 : ((f == 1) ? r1 : r2);
        float qq = wsum64(sdot4(xs, pr, av6, av4));
        float w = __expf(qq);
        den += w;
        acc.x += w * xs.x; acc.y += w * xs.y; acc.z += w * xs.z; acc.w += w * xs.w;
    }
    float inv = 1.f / den;
    float4 bv = *(const float4*)(bias + c);
    float ox = fmaf(acc.x, inv, bv.x), oy = fmaf(acc.y, inv, bv.y);
    float oz = fmaf(acc.z, inv, bv.z), ow = fmaf(acc.w, inv, bv.w);
    ((uint2*)(h2b + (size_t)d * 256))[lane] = make_uint2(bf16pack(ox, oy), bf16pack(oz, ow));
}

// ---------- GAT layer 2: wave per dst, 4 groups x 16 lanes x 2 dims/lane ----------
// Single loop; per-edge flow select (2 dims -> cheap).
__global__ __launch_bounds__(256) void k_gat32(const unsigned short* __restrict__ xc2,
        const int* __restrict__ rowptrF, const int* __restrict__ packed,
        const float* __restrict__ eaW, const float* __restrict__ loopW,
        const float* __restrict__ att, const float* __restrict__ bias,
        float* __restrict__ out, int n) {
    int wid = (blockIdx.x * blockDim.x + threadIdx.x) >> 6;
    if (wid >= n) return;
    int lane = threadIdx.x & 63;
    int g = lane >> 4, li = lane & 15;
    int d = wid;
    unsigned int uxl = ((const unsigned int*)(xc2 + (size_t)d * 64))[li];
    unsigned int uxr = ((const unsigned int*)(xc2 + (size_t)d * 64 + 32))[li];
    float xl0 = __uint_as_float(uxl << 16), xl1 = __uint_as_float(uxl & 0xFFFF0000u);
    float xr0 = __uint_as_float(uxr << 16), xr1 = __uint_as_float(uxr & 0xFFFF0000u);
    float2 avv = ((const float2*)att)[li];
    float a60 = 0.6f * avv.x, a61 = 0.6f * avv.y;
    float a40 = 0.4f * avv.x, a41 = 0.4f * avv.y;
    float2 e0 = ((const float2*)eaW)[li];
    float2 e1 = ((const float2*)(eaW + 32))[li];
    float2 e2 = ((const float2*)(eaW + 64))[li];
    float p00 = e0.x + xr0, p01 = e0.y + xr1;
    float p10 = e1.x + xr0, p11 = e1.y + xr1;
    float p20 = e2.x + xr0, p21 = e2.y + xr1;
    float den, acc0, acc1;
    {
        float2 lwv = ((const float2*)loopW)[li];
        float m0 = xl0 + xr0 + lwv.x, m1 = xl1 + xr1 + lwv.y;
        float q = a60 * m0 + a40 * fabsf(m0);
        q = fmaf(a61, m1, q); q = fmaf(a41, fabsf(m1), q);
        q += __shfl_xor(q, 1, 64); q += __shfl_xor(q, 2, 64);
        q += __shfl_xor(q, 4, 64); q += __shfl_xor(q, 8, 64);
        float wself = __expf(q);
        den  = (g == 0) ? wself : 0.f;
        acc0 = (g == 0) ? wself * xl0 : 0.f;
        acc1 = (g == 0) ? wself * xl1 : 0.f;
    }
    int pA = rowptrF[d * 3], pB = rowptrF[d * 3 + 3];
    int p = pA + g;
    for (; p + 4 < pB; p += 8) {   // 2 edges in flight per group (8 per wave)
        int pk0 = packed[p], pk1 = packed[p + 4];
        unsigned int ua = ((const unsigned int*)(xc2 + (size_t)(pk0 & 0xFFFF) * 64))[li];
        unsigned int ub = ((const unsigned int*)(xc2 + (size_t)(pk1 & 0xFFFF) * 64))[li];
        int fA = pk0 >> 16, fB = pk1 >> 16;
        float preA0 = (fA == 0) ? p00 : ((fA == 1) ? p10 : p20);
        float preA1 = (fA == 0) ? p01 : ((fA == 1) ? p11 : p21);
        float preB0 = (fB == 0) ? p00 : ((fB == 1) ? p10 : p20);
        float preB1 = (fB == 0) ? p01 : ((fB == 1) ? p11 : p21);
        float xa0 = __uint_as_float(ua << 16), xa1 = __uint_as_float(ua & 0xFFFF0000u);
        float xb0 = __uint_as_float(ub << 16), xb1 = __uint_as_float(ub & 0xFFFF0000u);
        float ma0 = xa0 + preA0, ma1 = xa1 + preA1;
        float mb0 = xb0 + preB0, mb1 = xb1 + preB1;
        float qa = a60 * ma0 + a40 * fabsf(ma0);
        qa = fmaf(a61, ma1, qa); qa = fmaf(a41, fabsf(ma1), qa);
        float qb = a60 * mb0 + a40 * fabsf(mb0);
        qb = fmaf(a61, mb1, qb); qb = fmaf(a41, fabsf(mb1), qb);
#pragma unroll
        for (int off = 1; off <= 8; off <<= 1) {
            qa += __shfl_xor(qa, off, 64);
            qb += __shfl_xor(qb, off, 64);
        }
        float wa = __expf(qa), wb = __expf(qb);
        den += wa + wb;
        acc0 = fmaf(wb, xb0, fmaf(wa, xa0, acc0));
        acc1 = fmaf(wb, xb1, fmaf(wa, xa1, acc1));
    }
    for (; p < pB; p += 4) {
        int pk = packed[p];
        unsigned int u = ((const unsigned int*)(xc2 + (size_t)(pk & 0xFFFF) * 64))[li];
        int f = pk >> 16;
        float pre0 = (f == 0) ? p00 : ((f == 1) ? p10 : p20);
        float pre1 = (f == 0) ? p01 : ((f == 1) ? p11 : p21);
        float x0 = __uint_as_float(u << 16), x1 = __uint_as_float(u & 0xFFFF0000u);
        float m0 = x0 + pre0, m1 = x1 + pre1;
        float q = a60 * m0 + a40 * fabsf(m0);
        q = fmaf(a61, m1, q); q = fmaf(a41, fabsf(m1), q);
        q += __shfl_xor(q, 1, 64); q += __shfl_xor(q, 2, 64);
        q += __shfl_xor(q, 4, 64); q += __shfl_xor(q, 8, 64);
        float w = __expf(q);
        den += w;
        acc0 = fmaf(w, x0, acc0);
        acc1 = fmaf(w, x1, acc1);
    }
    // combine the 4 groups
    acc0 += __shfl_xor(acc0, 16, 64); acc0 += __shfl_xor(acc0, 32, 64);
    acc1 += __shfl_xor(acc1, 16, 64); acc1 += __shfl_xor(acc1, 32, 64);
    den  += __shfl_xor(den, 16, 64);  den  += __shfl_xor(den, 32, 64);
    if (g == 0) {
        float2 bvv = ((const float2*)bias)[li];
        float inv = 1.f / den;
        float2 o;
        o.x = fmaf(acc0, inv, bvv.x);
        o.y = fmaf(acc1, inv, bvv.y);
        ((float2*)(out + (size_t)d * 32))[li] = o;
    }
}

// ---------- mean over nodes + policy head ----------
__global__ __launch_bounds__(256) void k_mean(const float* __restrict__ out2,
                                              float* __restrict__ gsum, int n) {
    __shared__ float sh[256];
    int t = threadIdx.x;
    int c = t & 31, g = t >> 5;
    float acc = 0.f;
    for (int nd = blockIdx.x * 8 + g; nd < n; nd += gridDim.x * 8)
        acc += out2[(size_t)nd * 32 + c];
    sh[t] = acc;
    __syncthreads();
    if (t < 32) {
        float s2 = 0.f;
#pragma unroll
        for (int gg = 0; gg < 8; ++gg) s2 += sh[gg * 32 + c];
        atomicAdd(&gsum[c], s2);
    }
}

__global__ void k_final(const float* __restrict__ gsum, const float* __restrict__ policy_W,
                        const float* __restrict__ policy_b, float* __restrict__ out, int n) {
    int t = threadIdx.x;  // 0..63 — one wave
    float invN = 1.0f / (float)n;
    float acc = policy_b[t];
    for (int cc = 0; cc < 32; ++cc) acc += gsum[cc] * invN * policy_W[cc * 64 + t];
    float mx = wmax64(acc);
    float ex = __expf(acc - mx);
    float s = wsum64(ex);
    out[t] = ex / s;
}

extern "C" void kernel_launch(void* const* d_in, const int* in_sizes, int n_in,
                              void* d_out, int out_size, void* d_ws, size_t ws_size,
                              hipStream_t stream) {
    const int* x          = (const int*)d_in[0];
    const int* edge_index = (const int*)d_in[1];
    const int* edge_attr  = (const int*)d_in[2];
    const float* text_emb = (const float*)d_in[3];
    const float* type_emb = (const float*)d_in[4];
    const float* flow_emb = (const float*)d_in[5];
    const float* pos_table= (const float*)d_in[6];
    const float* pos_W    = (const float*)d_in[7];
    const float* pos_b    = (const float*)d_in[8];
    const float* c1_Wl    = (const float*)d_in[9];
    const float* c1_bl    = (const float*)d_in[10];
    const float* c1_Wr    = (const float*)d_in[11];
    const float* c1_br    = (const float*)d_in[12];
    const float* c1_We    = (const float*)d_in[13];
    const float* c1_att   = (const float*)d_in[14];
    const float* c1_bias  = (const float*)d_in[15];
    const float* c2_Wl    = (const float*)d_in[16];
    const float* c2_bl    = (const float*)d_in[17];
    const float* c2_Wr    = (const float*)d_in[18];
    const float* c2_br    = (const float*)d_in[19];
    const float* c2_We    = (const float*)d_in[20];
    const float* c2_att   = (const float*)d_in[21];
    const float* c2_bias  = (const float*)d_in[22];
    const float* policy_W = (const float*)d_in[23];
    const float* policy_b = (const float*)d_in[24];
    float* out = (float*)d_out;

    const int N = in_sizes[0] / 2;   // 50000
    const int E = in_sizes[1] / 2;   // 800000
    const int n3 = 3 * N;

    // ---- workspace layout (256B-aligned chunks) ----
    char* base = (char*)d_ws;
    size_t off = 0;
    auto alloc = [&](size_t bytes) -> void* {
        void* p = base + off;
        off = (off + bytes + 255) & ~(size_t)255;
        return p;
    };
    unsigned short* xc1  = (unsigned short*)alloc((size_t)N * 512 * 2);  // xl1|xr1 bf16
    unsigned short* h2b  = (unsigned short*)alloc((size_t)N * 256 * 2);  // h2 bf16
    unsigned short* xc2  = (unsigned short*)alloc((size_t)N * 64 * 2);   // xl2|xr2 bf16
    float*          out2 = (float*)alloc((size_t)N * 32 * 4);
    unsigned short* Bt1  = (unsigned short*)alloc((size_t)512 * 128 * 2);
    unsigned short* Bt2  = (unsigned short*)alloc((size_t)64 * 256 * 2);
    // contiguous zero-region: cntF (3N) | cnt3 (4) | gsum (32)
    int*            zreg   = (int*)alloc((size_t)(n3 + 36) * 4);
    int*            cntF   = zreg;
    int*            cnt3   = zreg + n3;
    float*          gsum   = (float*)(zreg + n3 + 4);
    int*            rowptrF= (int*)alloc((size_t)(n3 + 1) * 4);
    int*            packed = (int*)alloc((size_t)E * 4);
    int*            bsum   = (int*)alloc(256 * 4);
    float*          eaW1   = (float*)alloc(768 * 4);
    float*          loopW1 = (float*)alloc(256 * 4);
    float*          eaW2   = (float*)alloc(96 * 4);
    float*          loopW2 = (float*)alloc(32 * 4);

    // ---- init (ws is poisoned 0xAA every call) ----
    hipMemsetAsync(zreg, 0, (size_t)(n3 + 36) * 4, stream);

    // ---- (dst,flow) histogram + flow counts; tables + weight conversion ----
    k_edges<<<(E + 255) / 256, 256, 0, stream>>>(edge_index, edge_attr, cntF, cnt3, E);
    k_prep_all<<<1 + (512 * 128 + 64 * 256) / 256, 256, 0, stream>>>(
        pos_table, pos_W, pos_b, flow_emb, c1_We, c2_We, cnt3,
        eaW1, loopW1, eaW2, loopW2, c1_Wl, c1_Wr, c2_Wl, c2_Wr, Bt1, Bt2, E);

    // ---- CSR build over 3N keys ((dst,flow)-sorted edge list) ----
    int nb = (n3 + 1023) / 1024;
    k_scan_block<<<nb, 256, 0, stream>>>(cntF, rowptrF, bsum, n3);
    k_scan_top<<<1, 64, 0, stream>>>(bsum, rowptrF, nb, n3);
    k_scan_add<<<(n3 + 255) / 256, 256, 0, stream>>>(rowptrF, bsum, cntF, n3);
    k_scatter<<<(E + 255) / 256, 256, 0, stream>>>(edge_index, edge_attr, cntF, packed, E);

    // ---- layer 1 ----
    k_gemm1<<<(N + 63) / 64, 256, 0, stream>>>(x, text_emb, type_emb, Bt1,
                                               c1_bl, c1_br, xc1, N);
    k_gat256<<<(N + 3) / 4, 256, 0, stream>>>(xc1, rowptrF, packed, eaW1, loopW1,
                                              c1_att, c1_bias, h2b, N);

    // ---- layer 2 ----
    k_gemm2<<<(N + 31) / 32, 256, 0, stream>>>(h2b, Bt2, c2_bl, c2_br, xc2, N);
    k_gat32<<<(N + 3) / 4, 256, 0, stream>>>(xc2, rowptrF, packed, eaW2, loopW2,
                                             c2_att, c2_bias, out2, N);

    // ---- readout ----
    k_mean<<<256, 256, 0, stream>>>(out2, gsum, N);
    k_final<<<1, 64, 0, stream>>>(gsum, policy_W, policy_b, out, N);
}